// Round 1
// baseline (1302.017 us; speedup 1.0000x reference)
//
#include <hip/hip_runtime.h>
#include <hip/hip_bf16.h>

typedef __hip_bfloat16 bf16;
typedef float v4f __attribute__((ext_vector_type(4)));
typedef short v8s __attribute__((ext_vector_type(8)));

#define B_ 4
#define S_ 1024
#define D_ 1024
#define H_ 16
#define DF_ 4096
#define KSEL 307

__device__ static inline void async16(bf16* lds, const bf16* g) {
    __builtin_amdgcn_global_load_lds(
        (const __attribute__((address_space(1))) void*)g,
        (__attribute__((address_space(3))) void*)lds, 16, 0, 0);
}

__device__ static inline unsigned short f2bu(float f) {
    __hip_bfloat16 h = __float2bfloat16(f);
    return *reinterpret_cast<unsigned short*>(&h);
}

// ---------------- fp32 -> bf16 convert ----------------
__global__ void __launch_bounds__(256) f2b_kernel(const float* __restrict__ in,
                                                  bf16* __restrict__ out, int n4) {
    int i = blockIdx.x * 256 + threadIdx.x;
    int stride = gridDim.x * 256;
    for (; i < n4; i += stride) {
        float4 v = ((const float4*)in)[i];
        ushort4 u = make_ushort4(f2bu(v.x), f2bu(v.y), f2bu(v.z), f2bu(v.w));
        ((ushort4*)out)[i] = u;
    }
}

// ---------------- LayerNorm (row of 1024) ----------------
__global__ void __launch_bounds__(256) ln_kernel(const float* __restrict__ x,
                                                 const float* __restrict__ g,
                                                 const float* __restrict__ be,
                                                 bf16* __restrict__ out) {
    int row = blockIdx.x;
    int tid = threadIdx.x;
    const float* xr = x + (long long)row * D_;
    float4 v = ((const float4*)xr)[tid];
    float s = v.x + v.y + v.z + v.w;
    float s2 = v.x*v.x + v.y*v.y + v.z*v.z + v.w*v.w;
    for (int off = 32; off > 0; off >>= 1) {
        s  += __shfl_down(s, off);
        s2 += __shfl_down(s2, off);
    }
    __shared__ float sh[4], sh2[4];
    int w = tid >> 6;
    if ((tid & 63) == 0) { sh[w] = s; sh2[w] = s2; }
    __syncthreads();
    float mean = (sh[0]+sh[1]+sh[2]+sh[3]) * (1.0f / D_);
    float ms   = (sh2[0]+sh2[1]+sh2[2]+sh2[3]) * (1.0f / D_);
    float var  = ms - mean*mean;
    float rs   = rsqrtf(var + 1e-5f);
    float4 gg = ((const float4*)g)[tid];
    float4 bb = ((const float4*)be)[tid];
    ushort4 o = make_ushort4(
        f2bu((v.x-mean)*rs*gg.x + bb.x),
        f2bu((v.y-mean)*rs*gg.y + bb.y),
        f2bu((v.z-mean)*rs*gg.z + bb.z),
        f2bu((v.w-mean)*rs*gg.w + bb.w));
    ((ushort4*)out)[(long long)row * 256 + tid] = o;
}

// ---------------- top-k threshold + masked softmax (in place, fp32 row of 1024) ---
__global__ void __launch_bounds__(256) topk_softmax(float* __restrict__ sc) {
    float* p = sc + (long long)blockIdx.x * 1024;
    int tid = threadIdx.x;
    float4 v4 = ((const float4*)p)[tid];
    float v[4] = {v4.x, v4.y, v4.z, v4.w};
    unsigned key[4];
#pragma unroll
    for (int j = 0; j < 4; ++j) {
        unsigned u = __float_as_uint(v[j]);
        key[j] = (u & 0x80000000u) ? ~u : (u | 0x80000000u);
    }
    __shared__ int hist[256];
    __shared__ int suf[256];
    __shared__ int sh_b, sh_above;
    unsigned prefix = 0;
    int need = KSEL;
    for (int pass = 0; pass < 2; ++pass) {
        int shift = 24 - 8 * pass;
        hist[tid] = 0;
        __syncthreads();
#pragma unroll
        for (int j = 0; j < 4; ++j) {
            bool cand = (pass == 0) || ((key[j] >> 24) == prefix);
            if (cand) atomicAdd(&hist[(key[j] >> shift) & 255], 1);
        }
        __syncthreads();
        if (tid < 64) {
            int h0 = hist[tid*4], h1 = hist[tid*4+1], h2 = hist[tid*4+2], h3 = hist[tid*4+3];
            int gs = h0 + h1 + h2 + h3;
            int sfx = gs;
            for (int off = 1; off < 64; off <<= 1) {
                int o = __shfl_down(sfx, off);
                if (tid + off < 64) sfx += o;
            }
            int above = sfx - gs;
            suf[tid*4+0] = above + gs;
            suf[tid*4+1] = above + h1 + h2 + h3;
            suf[tid*4+2] = above + h2 + h3;
            suf[tid*4+3] = above + h3;
        }
        __syncthreads();
        if (suf[tid] >= need && (tid == 255 || suf[tid+1] < need)) {
            sh_b = tid;
            sh_above = (tid == 255) ? 0 : suf[tid+1];
        }
        __syncthreads();
        prefix = (prefix << 8) | (unsigned)sh_b;
        need -= sh_above;
        __syncthreads();
    }
    // selected iff top 16 bits of key >= prefix
    float mx = fmaxf(fmaxf(v[0], v[1]), fmaxf(v[2], v[3]));
    for (int off = 32; off > 0; off >>= 1) mx = fmaxf(mx, __shfl_down(mx, off));
    __shared__ float shm[4], shs[4];
    int w = tid >> 6;
    if ((tid & 63) == 0) shm[w] = mx;
    __syncthreads();
    mx = fmaxf(fmaxf(shm[0], shm[1]), fmaxf(shm[2], shm[3]));
    float e[4];
    float sum = 0.f;
#pragma unroll
    for (int j = 0; j < 4; ++j) {
        bool sel = (key[j] >> 16) >= prefix;
        e[j] = sel ? expf(v[j] - mx) : 0.f;
        sum += e[j];
    }
    for (int off = 32; off > 0; off >>= 1) sum += __shfl_down(sum, off);
    if ((tid & 63) == 0) shs[w] = sum;
    __syncthreads();
    float inv = 1.0f / (shs[0] + shs[1] + shs[2] + shs[3]);
    float4 o;
    o.x = e[0]*inv; o.y = e[1]*inv; o.z = e[2]*inv; o.w = e[3]*inv;
    ((float4*)p)[tid] = o;
}

// ---------------- generic BT GEMM: C[m,n] = act(scale*sum_k A[m,k]B[n,k] + bias) + resid
struct GemmP {
    const bf16* A;      // bf16 A (if Af==null)
    const float* Af;    // fp32 A (staged+converted manually)
    const bf16* B;
    float* Cf;
    bf16* Cb;
    const float* bias;
    const float* resid;
    long long lda, ldb, ldc;
    int M, N, K;
    float scale;
    int bias_mode;   // 0 none, 1 per-col, 2 per-row
    int act;         // 0 none, 1 exact gelu
    int batch_mode;  // 0 linear, 1 scoresQK, 2 attnV
    long long sA, sB, sC;
};

__global__ void __launch_bounds__(256) gemm_bt(GemmP p) {
    __shared__ __align__(16) bf16 As[128 * 32];
    __shared__ __align__(16) bf16 Bs[128 * 32];
    int z = blockIdx.z;
    long long offA, offB, offC;
    if (p.batch_mode == 1) {
        int b = z >> 4, h = z & 15;
        offA = (long long)b * 1048576 + h * 64;
        offB = offA;
        offC = (long long)z * 1048576;
    } else if (p.batch_mode == 2) {
        int b = z >> 4, h = z & 15;
        offA = (long long)z * 1048576;
        offB = (long long)(h * 64) * 4096 + b * 1024;
        offC = (long long)b * 1048576 + h * 64;
    } else {
        offA = z * p.sA; offB = z * p.sB; offC = z * p.sC;
    }

    const int tid = threadIdx.x;
    const int w = tid >> 6, lane = tid & 63;
    const int tm = blockIdx.y * 128, tn = blockIdx.x * 128;
    const int q = lane >> 4, m16 = lane & 15;
    const int r0 = (w >> 1) * 64, c0 = (w & 1) * 64;
    const int srow = lane >> 2, scol = (lane & 3) * 8;

    v4f acc[4][4];
    v4f zero = {0.f, 0.f, 0.f, 0.f};
#pragma unroll
    for (int i = 0; i < 4; ++i)
#pragma unroll
        for (int j = 0; j < 4; ++j) acc[i][j] = zero;

    const bf16* Bbase = p.B + offB;
    for (int k0 = 0; k0 < p.K; k0 += 32) {
        if (p.Af == nullptr) {
            const bf16* Abase = p.A + offA;
            async16(&As[(w * 16) * 32],
                    Abase + (long long)(tm + w * 16 + srow) * p.lda + (k0 + scol));
            async16(&As[((w + 4) * 16) * 32],
                    Abase + (long long)(tm + (w + 4) * 16 + srow) * p.lda + (k0 + scol));
        } else {
            const float* Abase = p.Af + offA;
            int row = tid >> 1, half = (tid & 1) * 16;
            const float* src = Abase + (long long)(tm + row) * p.lda + (k0 + half);
            float tmp[16];
            *(float4*)&tmp[0]  = ((const float4*)src)[0];
            *(float4*)&tmp[4]  = ((const float4*)src)[1];
            *(float4*)&tmp[8]  = ((const float4*)src)[2];
            *(float4*)&tmp[12] = ((const float4*)src)[3];
            bf16* d = &As[row * 32 + half];
#pragma unroll
            for (int t = 0; t < 16; ++t) d[t] = __float2bfloat16(tmp[t]);
        }
        async16(&Bs[(w * 16) * 32],
                Bbase + (long long)(tn + w * 16 + srow) * p.ldb + (k0 + scol));
        async16(&Bs[((w + 4) * 16) * 32],
                Bbase + (long long)(tn + (w + 4) * 16 + srow) * p.ldb + (k0 + scol));
        __syncthreads();
        v8s af[4], bfr[4];
#pragma unroll
        for (int i = 0; i < 4; ++i)
            af[i] = *(const v8s*)&As[(r0 + 16 * i + m16) * 32 + q * 8];
#pragma unroll
        for (int j = 0; j < 4; ++j)
            bfr[j] = *(const v8s*)&Bs[(c0 + 16 * j + m16) * 32 + q * 8];
#pragma unroll
        for (int i = 0; i < 4; ++i)
#pragma unroll
            for (int j = 0; j < 4; ++j)
                acc[i][j] = __builtin_amdgcn_mfma_f32_16x16x32_bf16(af[i], bfr[j], acc[i][j], 0, 0, 0);
        __syncthreads();
    }

#pragma unroll
    for (int i = 0; i < 4; ++i) {
#pragma unroll
        for (int j = 0; j < 4; ++j) {
            int col = tn + c0 + 16 * j + m16;
            if (col >= p.N) continue;
            float bcol = (p.bias_mode == 1) ? p.bias[col] : 0.f;
#pragma unroll
            for (int r = 0; r < 4; ++r) {
                int row = tm + r0 + 16 * i + q * 4 + r;
                float v = acc[i][j][r] * p.scale;
                if (p.bias_mode == 1) v += bcol;
                else if (p.bias_mode == 2) v += p.bias[row];
                if (p.act) v = 0.5f * v * (1.0f + erff(v * 0.70710678118654752f));
                long long idx = offC + (long long)row * p.ldc + col;
                if (p.resid) v += p.resid[idx];
                if (p.Cf) p.Cf[idx] = v;
                if (p.Cb) p.Cb[idx] = __float2bfloat16(v);
            }
        }
    }
}

// ---------------- host ----------------
static void launch_gemm(hipStream_t stream, const bf16* A, const float* Af, const bf16* B,
                        float* Cf, bf16* Cb, const float* bias, int bias_mode,
                        const float* resid, long long lda, long long ldb, long long ldc,
                        int M, int N, int K, float scale, int act, int batch, int bmode) {
    GemmP P;
    P.A = A; P.Af = Af; P.B = B; P.Cf = Cf; P.Cb = Cb;
    P.bias = bias; P.resid = resid;
    P.lda = lda; P.ldb = ldb; P.ldc = ldc;
    P.M = M; P.N = N; P.K = K;
    P.scale = scale; P.bias_mode = bias_mode; P.act = act; P.batch_mode = bmode;
    P.sA = 0; P.sB = 0; P.sC = 0;
    dim3 g((N + 127) / 128, M / 128, batch);
    hipLaunchKernelGGL(gemm_bt, g, dim3(256), 0, stream, P);
}

extern "C" void kernel_launch(void* const* d_in, const int* in_sizes, int n_in,
                              void* d_out, int out_size, void* d_ws, size_t ws_size,
                              hipStream_t stream) {
    (void)in_sizes; (void)n_in; (void)out_size; (void)ws_size;
    const float* x  = (const float*)d_in[0];
    const float* Wq = (const float*)d_in[1];
    const float* bq = (const float*)d_in[2];
    const float* Wk = (const float*)d_in[3];
    const float* bk = (const float*)d_in[4];
    const float* Wv = (const float*)d_in[5];
    const float* bv = (const float*)d_in[6];
    const float* Wo = (const float*)d_in[7];
    const float* bo = (const float*)d_in[8];
    const float* W1 = (const float*)d_in[9];
    const float* b1 = (const float*)d_in[10];
    const float* Wm = (const float*)d_in[11];
    const float* bm = (const float*)d_in[12];
    const float* W2 = (const float*)d_in[13];
    const float* b2 = (const float*)d_in[14];
    const float* g1 = (const float*)d_in[15];
    const float* be1 = (const float*)d_in[16];
    const float* g2 = (const float*)d_in[17];
    const float* be2 = (const float*)d_in[18];

    char* ws = (char*)d_ws;
    const size_t MB = 1024 * 1024;
    bf16* WQb = (bf16*)(ws + 0 * MB);
    bf16* WKb = (bf16*)(ws + 2 * MB);
    bf16* WVb = (bf16*)(ws + 4 * MB);
    bf16* WOb = (bf16*)(ws + 6 * MB);
    bf16* W1b = (bf16*)(ws + 8 * MB);
    bf16* WMb = (bf16*)(ws + 16 * MB);
    bf16* W2b = (bf16*)(ws + 48 * MB);
    bf16* HB  = (bf16*)(ws + 56 * MB);   // h / h2 (bf16, [4096,1024])
    bf16* QB  = (bf16*)(ws + 64 * MB);
    bf16* KB  = (bf16*)(ws + 72 * MB);
    bf16* VT  = (bf16*)(ws + 80 * MB);   // V^T [1024, 4096]
    bf16* AT  = (bf16*)(ws + 88 * MB);   // attn@V output [4096,1024]
    float* X1 = (float*)(ws + 96 * MB);  // post-attn residual [4096,1024] fp32
    bf16* F1  = (bf16*)(ws + 112 * MB);  // [4096,4096]
    bf16* F2  = (bf16*)(ws + 144 * MB);  // [4096,4096]

    float* out_x  = (float*)d_out;               // [B,S,D]
    float* scores = out_x + 4194304;             // [B,H,S,S] scratch -> final attn

    // 1. weights -> bf16
    hipLaunchKernelGGL(f2b_kernel, dim3(1024), dim3(256), 0, stream, Wq, WQb, 262144);
    hipLaunchKernelGGL(f2b_kernel, dim3(1024), dim3(256), 0, stream, Wk, WKb, 262144);
    hipLaunchKernelGGL(f2b_kernel, dim3(1024), dim3(256), 0, stream, Wv, WVb, 262144);
    hipLaunchKernelGGL(f2b_kernel, dim3(1024), dim3(256), 0, stream, Wo, WOb, 262144);
    hipLaunchKernelGGL(f2b_kernel, dim3(1024), dim3(256), 0, stream, W1, W1b, 1048576);
    hipLaunchKernelGGL(f2b_kernel, dim3(1024), dim3(256), 0, stream, Wm, WMb, 4194304);
    hipLaunchKernelGGL(f2b_kernel, dim3(1024), dim3(256), 0, stream, W2, W2b, 1048576);

    // 2. LN1
    hipLaunchKernelGGL(ln_kernel, dim3(4096), dim3(256), 0, stream, x, g1, be1, HB);

    // 3. Q = h Wq^T + bq ; K = h Wk^T + bk   (bf16 out, [B*S, D])
    launch_gemm(stream, HB, nullptr, WQb, nullptr, QB, bq, 1, nullptr,
                1024, 1024, 1024, 4096, 1024, 1024, 1.f, 0, 1, 0);
    launch_gemm(stream, HB, nullptr, WKb, nullptr, KB, bk, 1, nullptr,
                1024, 1024, 1024, 4096, 1024, 1024, 1.f, 0, 1, 0);
    // V^T = Wv h^T + bv(row)  -> [1024 feat, 4096 bs]
    launch_gemm(stream, WVb, nullptr, HB, nullptr, VT, bv, 2, nullptr,
                1024, 1024, 4096, 1024, 4096, 1024, 1.f, 0, 1, 0);

    // 4. scores = Q K^T / 8  (fp32 into d_out attn region), batched over B*H
    launch_gemm(stream, QB, nullptr, KB, scores, nullptr, nullptr, 0, nullptr,
                1024, 1024, 1024, 1024, 1024, 64, 0.125f, 0, 64, 1);

    // 5. top-k + softmax in place
    hipLaunchKernelGGL(topk_softmax, dim3(65536), dim3(256), 0, stream, scores);

    // 6. att = attn @ V  (A fp32 from d_out, B = V^T), out bf16 [B,S,D]
    launch_gemm(stream, nullptr, scores, VT, nullptr, AT, nullptr, 0, nullptr,
                1024, 4096, 1024, 1024, 64, 1024, 1.f, 0, 64, 2);

    // 7. x1 = x + att Wo^T + bo  (fp32)
    launch_gemm(stream, AT, nullptr, WOb, X1, nullptr, bo, 1, x,
                1024, 1024, 1024, 4096, 1024, 1024, 1.f, 0, 1, 0);

    // 8. LN2
    hipLaunchKernelGGL(ln_kernel, dim3(4096), dim3(256), 0, stream, X1, g2, be2, HB);

    // 9. f1 = gelu(h2 W1^T + b1)   [4096,4096] bf16
    launch_gemm(stream, HB, nullptr, W1b, nullptr, F1, b1, 1, nullptr,
                1024, 1024, 4096, 4096, 4096, 1024, 1.f, 1, 1, 0);
    // 10. f2 = gelu(f1 Wm^T + bm)  [4096,4096] bf16
    launch_gemm(stream, F1, nullptr, WMb, nullptr, F2, bm, 1, nullptr,
                4096, 4096, 4096, 4096, 4096, 4096, 1.f, 1, 1, 0);
    // 11. out_x = x1 + f2 W2^T + b2  (fp32 -> d_out)
    launch_gemm(stream, F2, nullptr, W2b, out_x, nullptr, b2, 1, X1,
                4096, 4096, 1024, 4096, 1024, 4096, 1.f, 0, 1, 0);
}